// Round 2
// baseline (12306.786 us; speedup 1.0000x reference)
//
#include <hip/hip_runtime.h>
#include <hip/hip_bf16.h>

typedef __hip_bfloat16 bf16;

#define B_  4
#define L_  2048
#define D_  2048
#define H_  16
#define HD_ 128

// ---------------------------------------------------------------------------
// Dual-dtype access helpers. mode 0 = bf16, mode 1 = fp32. Mode is read from
// a device flag (wave-uniform) because the host cannot inspect device data
// under graph capture.
// ---------------------------------------------------------------------------
__device__ __forceinline__ float ldm(const void* p, size_t i, int m) {
    return m ? ((const float*)p)[i]
             : __bfloat162float(((const bf16*)p)[i]);
}
__device__ __forceinline__ void stm(void* p, size_t i, int m, float v) {
    if (m) ((float*)p)[i] = v;
    else   ((bf16*)p)[i] = __float2bfloat16(v);
}

// Detect whether the external buffers are fp32 or bf16 by examining x's first
// 64 halfwords as bf16: bf16-backed N(0,1) data has exponent <= ~129; fp32-
// backed data puts uniform mantissa bits in the even halfwords (~45% have
// exponent >= 141, incl. NaN/Inf patterns). flags[0]=mode, flags[1]=0.
__global__ void detect_kernel(const void* x, int* flags) {
    if (threadIdx.x == 0) {
        const unsigned short* u = (const unsigned short*)x;
        int fp32 = 0;
        for (int i = 0; i < 64; i++) {
            unsigned e = (u[i] >> 7) & 0xFF;
            if (e >= 141) fp32 = 1;
        }
        flags[0] = fp32;
        flags[1] = 0;
    }
}

// ---------------------------------------------------------------------------
// C = A (MxK) * Bw(NxK)^T, fp32 accumulate, dual-dtype in/out.
// 64x64 tile, BK=32, 256 threads, 4x4 micro-tile per thread.
// ---------------------------------------------------------------------------
__global__ __launch_bounds__(256) void gemm_bt_kernel(
    const void* __restrict__ A,  const int* __restrict__ aF,
    const void* __restrict__ Bw, const int* __restrict__ bF,
    void* __restrict__ C, size_t cOff, const int* __restrict__ cF,
    int N, int K)
{
    const int am = *aF, bm = *bF, cm = *cF;
    __shared__ float a_lds[64][33];
    __shared__ float b_lds[64][33];
    const int t  = threadIdx.x;
    const int m0 = blockIdx.y * 64;
    const int n0 = blockIdx.x * 64;
    const int tm = t >> 4;
    const int tn = t & 15;
    float acc[4][4] = {{0.f}};

    for (int k0 = 0; k0 < K; k0 += 32) {
        __syncthreads();
        #pragma unroll
        for (int i = 0; i < 8; i++) {
            int idx = t + i * 256;
            int r = idx >> 5, c = idx & 31;
            a_lds[r][c] = ldm(A,  (size_t)(m0 + r) * K + k0 + c, am);
            b_lds[r][c] = ldm(Bw, (size_t)(n0 + r) * K + k0 + c, bm);
        }
        __syncthreads();
        #pragma unroll
        for (int kk = 0; kk < 32; kk++) {
            float av[4], bv[4];
            #pragma unroll
            for (int i = 0; i < 4; i++) av[i] = a_lds[tm * 4 + i][kk];
            #pragma unroll
            for (int j = 0; j < 4; j++) bv[j] = b_lds[tn * 4 + j][kk];
            #pragma unroll
            for (int i = 0; i < 4; i++)
                #pragma unroll
                for (int j = 0; j < 4; j++)
                    acc[i][j] += av[i] * bv[j];
        }
    }
    #pragma unroll
    for (int i = 0; i < 4; i++)
        #pragma unroll
        for (int j = 0; j < 4; j++)
            stm(C, cOff + (size_t)(m0 + tm * 4 + i) * N + n0 + tn * 4 + j,
                cm, acc[i][j]);
}

// ---------------------------------------------------------------------------
// In-place rotary + RMS-norm over rows of 128 (one wave per row).
// l = (row / ldiv) % L.   q: ldiv=H.   k: ldiv=1.
// ---------------------------------------------------------------------------
__global__ __launch_bounds__(256) void rot_rms_kernel(
    void* __restrict__ p, size_t pOff, const int* __restrict__ pF,
    const void* __restrict__ cosb, const void* __restrict__ sinb,
    const int* __restrict__ eF, int ldiv)
{
    const int pm = *pF, em = *eF;
    const int row  = blockIdx.x * 4 + (threadIdx.x >> 6);
    const int lane = threadIdx.x & 63;
    const int l    = (row / ldiv) % L_;
    const size_t base = pOff + (size_t)row * HD_;

    float x1 = ldm(p, base + lane,      pm);
    float x2 = ldm(p, base + lane + 64, pm);
    float c  = ldm(cosb, (size_t)l * 64 + lane, em);
    float s  = ldm(sinb, (size_t)l * 64 + lane, em);
    float y1 =  x1 * c + x2 * s;
    float y2 = -x1 * s + x2 * c;

    float sq = y1 * y1 + y2 * y2;
    #pragma unroll
    for (int off = 32; off > 0; off >>= 1) sq += __shfl_xor(sq, off);
    float rinv = rsqrtf(sq * (1.0f / 128.0f) + 1.1920929e-07f);

    stm(p, base + lane,      pm, y1 * rinv);
    stm(p, base + lane + 64, pm, y2 * rinv);
}

// ---------------------------------------------------------------------------
// Causal MQA flash attention. q (internal bf16) read AND overwritten in-place
// (safe: each (b,l0,h) q-slice is read by exactly its own block, staged into
// LDS behind barriers before the epilogue overwrites it).
// k/v come from d_out regions (dual dtype).
// ---------------------------------------------------------------------------
__global__ __launch_bounds__(256) void attn_kernel(
    const bf16* __restrict__ q,
    const void* __restrict__ kv, size_t kOff, size_t vOff,
    const int* __restrict__ kvF,
    bf16* __restrict__ o)
{
    const int kvm = *kvF;
    const int l0 = blockIdx.x * 32;
    const int h  = blockIdx.y;
    const int b  = blockIdx.z;
    const int t  = threadIdx.x;
    const int m  = t >> 3;
    const int g  = t & 7;

    __shared__ float qls[32][132];
    __shared__ float kls[32][129];
    __shared__ float vls[32][129];
    __shared__ float pls[32][34];

    for (int i = t; i < 32 * 128; i += 256) {
        int r = i >> 7, c = i & 127;
        qls[r][c] = __bfloat162float(q[(size_t)(b * L_ + l0 + r) * D_ + h * HD_ + c]);
    }

    float m_i = -1e30f, l_i = 0.f;
    float o_acc[16];
    #pragma unroll
    for (int i = 0; i < 16; i++) o_acc[i] = 0.f;
    const float scale = 0.08838834764831845f;  // 1/sqrt(128)

    for (int kb = 0; kb <= l0; kb += 32) {
        __syncthreads();
        for (int i = t; i < 32 * 128; i += 256) {
            int r = i >> 7, c = i & 127;
            size_t idx = (size_t)(b * L_ + kb + r) * HD_ + c;
            kls[r][c] = ldm(kv, kOff + idx, kvm);
            vls[r][c] = ldm(kv, vOff + idx, kvm);
        }
        __syncthreads();

        float sacc[4] = {0.f, 0.f, 0.f, 0.f};
        for (int j = 0; j < 128; j++) {
            float qv = qls[m][j];
            #pragma unroll
            for (int sub = 0; sub < 4; sub++)
                sacc[sub] += qv * kls[g * 4 + sub][j];
        }
        float s[4];
        #pragma unroll
        for (int sub = 0; sub < 4; sub++) {
            int kpos = kb + g * 4 + sub;
            s[sub] = (kpos <= l0 + m) ? sacc[sub] * scale : -1e30f;
        }

        float mx = fmaxf(fmaxf(s[0], s[1]), fmaxf(s[2], s[3]));
        #pragma unroll
        for (int off = 1; off < 8; off <<= 1) mx = fmaxf(mx, __shfl_xor(mx, off));
        float m_new = fmaxf(m_i, mx);
        float alpha = __expf(m_i - m_new);

        float ps = 0.f;
        #pragma unroll
        for (int sub = 0; sub < 4; sub++) {
            float pexp = __expf(s[sub] - m_new);
            ps += pexp;
            pls[m][g * 4 + sub] = pexp;
        }
        #pragma unroll
        for (int off = 1; off < 8; off <<= 1) ps += __shfl_xor(ps, off);
        l_i = l_i * alpha + ps;
        m_i = m_new;
        #pragma unroll
        for (int cc = 0; cc < 16; cc++) o_acc[cc] *= alpha;
        __syncthreads();

        for (int n = 0; n < 32; n++) {
            float pw = pls[m][n];
            #pragma unroll
            for (int cc = 0; cc < 16; cc++)
                o_acc[cc] += pw * vls[n][g + 8 * cc];
        }
    }

    float inv = 1.f / l_i;
    #pragma unroll
    for (int cc = 0; cc < 16; cc++) {
        int c = g + 8 * cc;
        o[(size_t)(b * L_ + l0 + m) * D_ + h * HD_ + c] =
            __float2bfloat16(o_acc[cc] * inv);
    }
}

// ---------------------------------------------------------------------------
extern "C" void kernel_launch(void* const* d_in, const int* in_sizes, int n_in,
                              void* d_out, int out_size, void* d_ws, size_t ws_size,
                              hipStream_t stream)
{
    const void* x    = d_in[0];
    const void* cosb = d_in[1];
    const void* sinb = d_in[2];
    const void* Wq   = d_in[3];
    const void* Wk   = d_in[4];
    const void* Wv   = d_in[5];
    const void* Wo   = d_in[6];

    // ws layout: [flags: 2 ints, padded to 256 B][qbuf: B*L*D bf16 = 32 MiB]
    int*  flags = (int*)d_ws;
    bf16* qbuf  = (bf16*)((char*)d_ws + 256);
    const int* EXT  = flags;      // detected external dtype mode
    const int* INT0 = flags + 1;  // always 0 (bf16 internal)

    // d_out element offsets (dtype-agnostic)
    const size_t kOff = (size_t)B_ * L_ * D_;
    const size_t vOff = kOff + (size_t)B_ * L_ * HD_;

    const int M = B_ * L_;  // 8192

    detect_kernel<<<1, 64, 0, stream>>>(x, flags);

    // Projections: q -> qbuf (bf16), k/v raw -> d_out regions (external dtype)
    gemm_bt_kernel<<<dim3(D_ / 64,  M / 64), 256, 0, stream>>>(
        x, EXT, Wq, EXT, qbuf, 0, INT0, D_, D_);
    gemm_bt_kernel<<<dim3(HD_ / 64, M / 64), 256, 0, stream>>>(
        x, EXT, Wk, EXT, d_out, kOff, EXT, HD_, D_);
    gemm_bt_kernel<<<dim3(HD_ / 64, M / 64), 256, 0, stream>>>(
        x, EXT, Wv, EXT, d_out, vOff, EXT, HD_, D_);

    // rotary + rmsnorm (in place)
    rot_rms_kernel<<<(M * H_) / 4, 256, 0, stream>>>(
        qbuf, 0, INT0, cosb, sinb, EXT, H_);
    rot_rms_kernel<<<M / 4, 256, 0, stream>>>(
        d_out, kOff, EXT, cosb, sinb, EXT, 1);

    // causal MQA attention: reads qbuf, writes output back into qbuf in place
    attn_kernel<<<dim3(L_ / 32, H_, B_), 256, 0, stream>>>(
        qbuf, d_out, kOff, vOff, EXT, qbuf);

    // O projection: attention output (qbuf) @ Wo^T -> out
    gemm_bt_kernel<<<dim3(D_ / 64, M / 64), 256, 0, stream>>>(
        qbuf, INT0, Wo, EXT, d_out, 0, EXT, D_, D_);
}

// Round 3
// 1140.379 us; speedup vs baseline: 10.7918x; 10.7918x over previous
//
#include <hip/hip_runtime.h>
#include <hip/hip_bf16.h>

typedef __hip_bfloat16 bf16;
typedef __attribute__((ext_vector_type(8))) short s8v;   // 8 bf16 = 16 B (MFMA A/B frag)
typedef __attribute__((ext_vector_type(4))) short s4v;   // 4 bf16 = 8 B
typedef __attribute__((ext_vector_type(4))) float f4v;   // MFMA C/D frag

#define B_  4
#define L_  2048
#define D_  2048
#define H_  16
#define HD_ 128

// ---------------------------------------------------------------------------
// Dual-dtype helpers: mode 0 = bf16, 1 = fp32 (detected at runtime on device).
// ---------------------------------------------------------------------------
__device__ __forceinline__ float ldm(const void* p, size_t i, int m) {
    return m ? ((const float*)p)[i]
             : __bfloat162float(((const bf16*)p)[i]);
}
__device__ __forceinline__ void stm(void* p, size_t i, int m, float v) {
    if (m) ((float*)p)[i] = v;
    else   ((bf16*)p)[i] = __float2bfloat16(v);
}

__global__ void detect_kernel(const void* x, int* flags) {
    if (threadIdx.x == 0) {
        const unsigned short* u = (const unsigned short*)x;
        int fp32 = 0;
        for (int i = 0; i < 64; i++) {
            unsigned e = (u[i] >> 7) & 0xFF;
            if (e >= 141) fp32 = 1;
        }
        flags[0] = fp32;
        flags[1] = 0;
    }
}

// ---------------------------------------------------------------------------
// MFMA GEMM: C = A (MxK) * Bw (NxK)^T. 128x128 tile, BK=32, 256 threads.
// 4 waves in 2x2; each wave 64x64 = 4x4 tiles of 16x16x32 bf16 MFMA.
// LDS rows padded +8 bf16 (16 B): keeps ds_read_b128 alignment, stride
// 20 dwords -> lanes tile all 32 banks 2-way (free).
// ---------------------------------------------------------------------------
__global__ __launch_bounds__(256) void gemm_bt_kernel(
    const void* __restrict__ A,  const int* __restrict__ aF,
    const void* __restrict__ Bw, const int* __restrict__ bF,
    void* __restrict__ C, size_t cOff, const int* __restrict__ cF,
    int N, int K)
{
    const int am = *aF, bm = *bF, cm = *cF;
    __shared__ bf16 a_lds[128][40];
    __shared__ bf16 b_lds[128][40];
    const int t  = threadIdx.x;
    const int m0 = blockIdx.y * 128;
    const int n0 = blockIdx.x * 128;
    const int w  = t >> 6, ln = t & 63;
    const int wr = w >> 1, wc = w & 1;
    const int fr = ln & 15;      // fragment row within 16-tile
    const int kg = ln >> 4;      // k-group (0..3)
    const int sr = t >> 1;       // staging row 0..127
    const int sc = (t & 1) * 16; // staging col 0/16

    f4v acc[4][4];
    #pragma unroll
    for (int i = 0; i < 4; i++)
        #pragma unroll
        for (int j = 0; j < 4; j++)
            #pragma unroll
            for (int r = 0; r < 4; r++) acc[i][j][r] = 0.f;

    for (int k0 = 0; k0 < K; k0 += 32) {
        __syncthreads();
        // ---- stage A tile ----
        {
            size_t g = (size_t)(m0 + sr) * K + k0 + sc;
            bf16 tmp[16];
            if (am) {
                const f4v* p = (const f4v*)((const float*)A + g);
                #pragma unroll
                for (int q = 0; q < 4; q++) {
                    f4v f = p[q];
                    #pragma unroll
                    for (int e = 0; e < 4; e++) tmp[q * 4 + e] = __float2bfloat16(f[e]);
                }
            } else {
                const s8v* p = (const s8v*)((const bf16*)A + g);
                *(s8v*)&tmp[0] = p[0];
                *(s8v*)&tmp[8] = p[1];
            }
            *(s8v*)&a_lds[sr][sc]     = *(s8v*)&tmp[0];
            *(s8v*)&a_lds[sr][sc + 8] = *(s8v*)&tmp[8];
        }
        // ---- stage B tile ----
        {
            size_t g = (size_t)(n0 + sr) * K + k0 + sc;
            bf16 tmp[16];
            if (bm) {
                const f4v* p = (const f4v*)((const float*)Bw + g);
                #pragma unroll
                for (int q = 0; q < 4; q++) {
                    f4v f = p[q];
                    #pragma unroll
                    for (int e = 0; e < 4; e++) tmp[q * 4 + e] = __float2bfloat16(f[e]);
                }
            } else {
                const s8v* p = (const s8v*)((const bf16*)Bw + g);
                *(s8v*)&tmp[0] = p[0];
                *(s8v*)&tmp[8] = p[1];
            }
            *(s8v*)&b_lds[sr][sc]     = *(s8v*)&tmp[0];
            *(s8v*)&b_lds[sr][sc + 8] = *(s8v*)&tmp[8];
        }
        __syncthreads();

        s8v af[4], bf[4];
        #pragma unroll
        for (int i = 0; i < 4; i++)
            af[i] = *(const s8v*)&a_lds[wr * 64 + i * 16 + fr][kg * 8];
        #pragma unroll
        for (int j = 0; j < 4; j++)
            bf[j] = *(const s8v*)&b_lds[wc * 64 + j * 16 + fr][kg * 8];
        #pragma unroll
        for (int i = 0; i < 4; i++)
            #pragma unroll
            for (int j = 0; j < 4; j++)
                acc[i][j] = __builtin_amdgcn_mfma_f32_16x16x32_bf16(
                    af[i], bf[j], acc[i][j], 0, 0, 0);
    }

    // C-layout: col = lane&15, row = (lane>>4)*4 + reg   [m89-verified]
    #pragma unroll
    for (int i = 0; i < 4; i++)
        #pragma unroll
        for (int j = 0; j < 4; j++)
            #pragma unroll
            for (int r = 0; r < 4; r++) {
                int row = m0 + wr * 64 + i * 16 + kg * 4 + r;
                int col = n0 + wc * 64 + j * 16 + fr;
                stm(C, cOff + (size_t)row * N + col, cm, acc[i][j][r]);
            }
}

// ---------------------------------------------------------------------------
// rotary + RMS-norm (unchanged from passing round)
// ---------------------------------------------------------------------------
__global__ __launch_bounds__(256) void rot_rms_kernel(
    void* __restrict__ p, size_t pOff, const int* __restrict__ pF,
    const void* __restrict__ cosb, const void* __restrict__ sinb,
    const int* __restrict__ eF, int ldiv)
{
    const int pm = *pF, em = *eF;
    const int row  = blockIdx.x * 4 + (threadIdx.x >> 6);
    const int lane = threadIdx.x & 63;
    const int l    = (row / ldiv) % L_;
    const size_t base = pOff + (size_t)row * HD_;

    float x1 = ldm(p, base + lane,      pm);
    float x2 = ldm(p, base + lane + 64, pm);
    float c  = ldm(cosb, (size_t)l * 64 + lane, em);
    float s  = ldm(sinb, (size_t)l * 64 + lane, em);
    float y1 =  x1 * c + x2 * s;
    float y2 = -x1 * s + x2 * c;

    float sq = y1 * y1 + y2 * y2;
    #pragma unroll
    for (int off = 32; off > 0; off >>= 1) sq += __shfl_xor(sq, off);
    float rinv = rsqrtf(sq * (1.0f / 128.0f) + 1.1920929e-07f);

    stm(p, base + lane,      pm, y1 * rinv);
    stm(p, base + lane + 64, pm, y2 * rinv);
}

// ---------------------------------------------------------------------------
// V transpose: newv [B][L][HD] (ext dtype) -> vt [B][HD][L] bf16
// ---------------------------------------------------------------------------
__global__ __launch_bounds__(256) void transpose_v_kernel(
    const void* __restrict__ v, size_t vOff, const int* __restrict__ vF,
    bf16* __restrict__ vt)
{
    const int m = *vF;
    const int l0 = blockIdx.x * 32, c0 = blockIdx.y * 32, b = blockIdx.z;
    __shared__ bf16 tile[32][36];
    const int t = threadIdx.x;
    {
        int r = t >> 3, c4 = (t & 7) * 4;
        size_t g = vOff + (size_t)(b * L_ + l0 + r) * HD_ + c0 + c4;
        #pragma unroll
        for (int e = 0; e < 4; e++)
            tile[r][c4 + e] = __float2bfloat16(ldm(v, g + e, m));
    }
    __syncthreads();
    {
        int c = t >> 3, r4 = (t & 7) * 4;
        bf16 tmp[4];
        #pragma unroll
        for (int e = 0; e < 4; e++) tmp[e] = tile[r4 + e][c];
        *(s4v*)&vt[(size_t)(b * HD_ + c0 + c) * L_ + l0 + r4] = *(s4v*)&tmp[0];
    }
}

// ---------------------------------------------------------------------------
// MFMA causal flash attention. Block = (64 q-rows, h, b), 4 waves.
// Wave w owns q-row strip 16w..16w+15 (wave-private softmax stats).
// Q frags live in registers (loop-invariant). K staged row-major; V staged
// from pre-transposed vt so PV B-frags are contiguous ds_read_b128.
// P round-trips through LDS (C-layout -> A-layout), m120-verified pattern.
// ---------------------------------------------------------------------------
__global__ __launch_bounds__(256) void attn_kernel(
    const bf16* __restrict__ q,
    const void* __restrict__ kv, size_t kOff, const int* __restrict__ kvF,
    const bf16* __restrict__ vt,
    bf16* __restrict__ o)
{
    const int kvm = *kvF;
    const int l0 = blockIdx.x * 64;
    const int h  = blockIdx.y, b = blockIdx.z;
    const int t  = threadIdx.x, w = t >> 6, ln = t & 63;
    const int fr = ln & 15, kg = ln >> 4;

    __shared__ bf16 k_lds[64][136];   // row-major K tile (+8 pad)
    __shared__ bf16 vt_lds[128][72];  // V^T tile: [hd col][k] (+8 pad)
    __shared__ bf16 p_lds[64][72];    // P tile (+8 pad)

    // Q fragments: row = l0 + 16w + fr, k = kst*32 + kg*8 .. +7
    s8v qf[4];
    {
        size_t base = (size_t)(b * L_ + l0 + 16 * w + fr) * D_ + h * HD_ + kg * 8;
        #pragma unroll
        for (int kst = 0; kst < 4; kst++)
            qf[kst] = *(const s8v*)(q + base + kst * 32);
    }

    float m_i[4], l_i[4];
    #pragma unroll
    for (int r = 0; r < 4; r++) { m_i[r] = -3.0e38f; l_i[r] = 0.f; }
    f4v o_acc[8];
    #pragma unroll
    for (int nt = 0; nt < 8; nt++)
        #pragma unroll
        for (int r = 0; r < 4; r++) o_acc[nt][r] = 0.f;

    const float scale = 0.08838834764831845f;  // 1/sqrt(128)

    for (int kb = 0; kb <= l0; kb += 64) {
        __syncthreads();
        // ---- stage K tile (64x128, dual dtype) ----
        {
            int r = t >> 2, c0 = (t & 3) * 32;
            size_t g = kOff + (size_t)(b * L_ + kb + r) * HD_ + c0;
            bf16 tmp[32];
            if (kvm) {
                const f4v* p = (const f4v*)((const float*)kv + g);
                #pragma unroll
                for (int qq = 0; qq < 8; qq++) {
                    f4v f = p[qq];
                    #pragma unroll
                    for (int e = 0; e < 4; e++) tmp[qq * 4 + e] = __float2bfloat16(f[e]);
                }
            } else {
                const s8v* p = (const s8v*)((const bf16*)kv + g);
                #pragma unroll
                for (int qq = 0; qq < 4; qq++) *(s8v*)&tmp[qq * 8] = p[qq];
            }
            #pragma unroll
            for (int s = 0; s < 4; s++)
                *(s8v*)&k_lds[r][c0 + s * 8] = *(s8v*)&tmp[s * 8];
        }
        // ---- stage V^T tile (128 hd-rows x 64 k, bf16) ----
        {
            int c = t >> 1, s0 = (t & 1) * 32;
            const s8v* p = (const s8v*)(vt + (size_t)(b * HD_ + c) * L_ + kb + s0);
            #pragma unroll
            for (int s = 0; s < 4; s++)
                *(s8v*)&vt_lds[c][s0 + s * 8] = p[s];
        }
        __syncthreads();

        // ---- S = Q K^T for this wave's 16-row strip (4 col-tiles) ----
        f4v sacc[4];
        #pragma unroll
        for (int j = 0; j < 4; j++)
            #pragma unroll
            for (int r = 0; r < 4; r++) sacc[j][r] = 0.f;
        #pragma unroll
        for (int kst = 0; kst < 4; kst++) {
            #pragma unroll
            for (int j = 0; j < 4; j++) {
                s8v bf = *(const s8v*)&k_lds[j * 16 + fr][kst * 32 + kg * 8];
                sacc[j] = __builtin_amdgcn_mfma_f32_16x16x32_bf16(
                    qf[kst], bf, sacc[j], 0, 0, 0);
            }
        }

        // ---- online softmax (rows wave-private; reduce over lane&15) ----
        const bool diag = (kb == l0);
        float sv[4][4];
        #pragma unroll
        for (int j = 0; j < 4; j++)
            #pragma unroll
            for (int r = 0; r < 4; r++) {
                float v = sacc[j][r] * scale;
                if (diag && (j * 16 + fr) > (16 * w + kg * 4 + r)) v = -1.0e30f;
                sv[j][r] = v;
            }
        float alpha[4], rsum[4];
        #pragma unroll
        for (int r = 0; r < 4; r++) {
            float mr = fmaxf(fmaxf(sv[0][r], sv[1][r]), fmaxf(sv[2][r], sv[3][r]));
            #pragma unroll
            for (int off = 1; off < 16; off <<= 1) mr = fmaxf(mr, __shfl_xor(mr, off));
            float mn = fmaxf(m_i[r], mr);
            alpha[r] = __expf(m_i[r] - mn);
            m_i[r] = mn;
            rsum[r] = 0.f;
        }
        #pragma unroll
        for (int j = 0; j < 4; j++)
            #pragma unroll
            for (int r = 0; r < 4; r++) {
                float pe = __expf(sv[j][r] - m_i[r]);
                rsum[r] += pe;
                p_lds[16 * w + kg * 4 + r][j * 16 + fr] = __float2bfloat16(pe);
            }
        #pragma unroll
        for (int r = 0; r < 4; r++) {
            float rs = rsum[r];
            #pragma unroll
            for (int off = 1; off < 16; off <<= 1) rs += __shfl_xor(rs, off);
            l_i[r] = l_i[r] * alpha[r] + rs;
        }
        #pragma unroll
        for (int nt = 0; nt < 8; nt++)
            #pragma unroll
            for (int r = 0; r < 4; r++) o_acc[nt][r] *= alpha[r];

        // ---- O += P V  (P rows wave-private; V^T frags contiguous) ----
        #pragma unroll
        for (int kst2 = 0; kst2 < 2; kst2++) {
            s8v pf = *(const s8v*)&p_lds[16 * w + fr][kst2 * 32 + kg * 8];
            #pragma unroll
            for (int nt = 0; nt < 8; nt++) {
                s8v vf = *(const s8v*)&vt_lds[nt * 16 + fr][kst2 * 32 + kg * 8];
                o_acc[nt] = __builtin_amdgcn_mfma_f32_16x16x32_bf16(
                    pf, vf, o_acc[nt], 0, 0, 0);
            }
        }
    }

    #pragma unroll
    for (int r = 0; r < 4; r++) l_i[r] = 1.f / l_i[r];
    #pragma unroll
    for (int nt = 0; nt < 8; nt++)
        #pragma unroll
        for (int r = 0; r < 4; r++) {
            int row = l0 + 16 * w + kg * 4 + r;
            int col = h * HD_ + nt * 16 + fr;
            o[(size_t)(b * L_ + row) * D_ + col] =
                __float2bfloat16(o_acc[nt][r] * l_i[r]);
        }
}

// ---------------------------------------------------------------------------
extern "C" void kernel_launch(void* const* d_in, const int* in_sizes, int n_in,
                              void* d_out, int out_size, void* d_ws, size_t ws_size,
                              hipStream_t stream)
{
    const void* x    = d_in[0];
    const void* cosb = d_in[1];
    const void* sinb = d_in[2];
    const void* Wq   = d_in[3];
    const void* Wk   = d_in[4];
    const void* Wv   = d_in[5];
    const void* Wo   = d_in[6];

    // ws: [flags 256 B][vtbuf: B*HD*L bf16 = 2 MiB][qbuf: B*L*D bf16 = 32 MiB]
    int*  flags = (int*)d_ws;
    bf16* vtbuf = (bf16*)((char*)d_ws + 256);
    bf16* qbuf  = vtbuf + (size_t)B_ * HD_ * L_;
    const int* EXT  = flags;
    const int* INT0 = flags + 1;

    const size_t kOff = (size_t)B_ * L_ * D_;
    const size_t vOff = kOff + (size_t)B_ * L_ * HD_;
    const int M = B_ * L_;  // 8192

    detect_kernel<<<1, 64, 0, stream>>>(x, flags);

    gemm_bt_kernel<<<dim3(D_ / 128,  M / 128), 256, 0, stream>>>(
        x, EXT, Wq, EXT, qbuf, 0, INT0, D_, D_);
    gemm_bt_kernel<<<dim3(HD_ / 128, M / 128), 256, 0, stream>>>(
        x, EXT, Wk, EXT, d_out, kOff, EXT, HD_, D_);
    gemm_bt_kernel<<<dim3(HD_ / 128, M / 128), 256, 0, stream>>>(
        x, EXT, Wv, EXT, d_out, vOff, EXT, HD_, D_);

    rot_rms_kernel<<<(M * H_) / 4, 256, 0, stream>>>(
        qbuf, 0, INT0, cosb, sinb, EXT, H_);
    rot_rms_kernel<<<M / 4, 256, 0, stream>>>(
        d_out, kOff, EXT, cosb, sinb, EXT, 1);

    transpose_v_kernel<<<dim3(L_ / 32, HD_ / 32, B_), 256, 0, stream>>>(
        d_out, vOff, EXT, vtbuf);

    attn_kernel<<<dim3(L_ / 64, H_, B_), 256, 0, stream>>>(
        qbuf, d_out, kOff, EXT, vtbuf, qbuf);

    gemm_bt_kernel<<<dim3(D_ / 128, M / 128), 256, 0, stream>>>(
        qbuf, INT0, Wo, EXT, d_out, 0, EXT, D_, D_);
}

// Round 4
// 965.045 us; speedup vs baseline: 12.7525x; 1.1817x over previous
//
#include <hip/hip_runtime.h>
#include <hip/hip_bf16.h>

typedef __hip_bfloat16 bf16;
typedef __attribute__((ext_vector_type(8))) short s8v;   // 8 bf16 = 16 B (MFMA A/B frag)
typedef __attribute__((ext_vector_type(4))) short s4v;   // 4 bf16 = 8 B
typedef __attribute__((ext_vector_type(4))) float f4v;   // MFMA C/D frag

#define B_  4
#define L_  2048
#define D_  2048
#define H_  16
#define HD_ 128

// ---------------------------------------------------------------------------
// Dual-dtype helpers: mode 0 = bf16, 1 = fp32 (detected at runtime on device).
// ---------------------------------------------------------------------------
__device__ __forceinline__ float ldm(const void* p, size_t i, int m) {
    return m ? ((const float*)p)[i]
             : __bfloat162float(((const bf16*)p)[i]);
}
__device__ __forceinline__ void stm(void* p, size_t i, int m, float v) {
    if (m) ((float*)p)[i] = v;
    else   ((bf16*)p)[i] = __float2bfloat16(v);
}

__global__ void detect_kernel(const void* x, int* flags) {
    if (threadIdx.x == 0) {
        const unsigned short* u = (const unsigned short*)x;
        int fp32 = 0;
        for (int i = 0; i < 64; i++) {
            unsigned e = (u[i] >> 7) & 0xFF;
            if (e >= 141) fp32 = 1;
        }
        flags[0] = fp32;
        flags[1] = 0;
    }
}

// ---------------------------------------------------------------------------
// MFMA GEMM: C = A (MxK) * Bw (NxK)^T. 128x128 tile, BK=32, 256 threads.
// (unchanged from round 3 — measure its dispatches next round)
// ---------------------------------------------------------------------------
__global__ __launch_bounds__(256) void gemm_bt_kernel(
    const void* __restrict__ A,  const int* __restrict__ aF,
    const void* __restrict__ Bw, const int* __restrict__ bF,
    void* __restrict__ C, size_t cOff, const int* __restrict__ cF,
    int N, int K)
{
    const int am = *aF, bm = *bF, cm = *cF;
    __shared__ bf16 a_lds[128][40];
    __shared__ bf16 b_lds[128][40];
    const int t  = threadIdx.x;
    const int m0 = blockIdx.y * 128;
    const int n0 = blockIdx.x * 128;
    const int w  = t >> 6, ln = t & 63;
    const int wr = w >> 1, wc = w & 1;
    const int fr = ln & 15;
    const int kg = ln >> 4;
    const int sr = t >> 1;
    const int sc = (t & 1) * 16;

    f4v acc[4][4];
    #pragma unroll
    for (int i = 0; i < 4; i++)
        #pragma unroll
        for (int j = 0; j < 4; j++)
            #pragma unroll
            for (int r = 0; r < 4; r++) acc[i][j][r] = 0.f;

    for (int k0 = 0; k0 < K; k0 += 32) {
        __syncthreads();
        {
            size_t g = (size_t)(m0 + sr) * K + k0 + sc;
            bf16 tmp[16];
            if (am) {
                const f4v* p = (const f4v*)((const float*)A + g);
                #pragma unroll
                for (int q = 0; q < 4; q++) {
                    f4v f = p[q];
                    #pragma unroll
                    for (int e = 0; e < 4; e++) tmp[q * 4 + e] = __float2bfloat16(f[e]);
                }
            } else {
                const s8v* p = (const s8v*)((const bf16*)A + g);
                *(s8v*)&tmp[0] = p[0];
                *(s8v*)&tmp[8] = p[1];
            }
            *(s8v*)&a_lds[sr][sc]     = *(s8v*)&tmp[0];
            *(s8v*)&a_lds[sr][sc + 8] = *(s8v*)&tmp[8];
        }
        {
            size_t g = (size_t)(n0 + sr) * K + k0 + sc;
            bf16 tmp[16];
            if (bm) {
                const f4v* p = (const f4v*)((const float*)Bw + g);
                #pragma unroll
                for (int q = 0; q < 4; q++) {
                    f4v f = p[q];
                    #pragma unroll
                    for (int e = 0; e < 4; e++) tmp[q * 4 + e] = __float2bfloat16(f[e]);
                }
            } else {
                const s8v* p = (const s8v*)((const bf16*)Bw + g);
                *(s8v*)&tmp[0] = p[0];
                *(s8v*)&tmp[8] = p[1];
            }
            *(s8v*)&b_lds[sr][sc]     = *(s8v*)&tmp[0];
            *(s8v*)&b_lds[sr][sc + 8] = *(s8v*)&tmp[8];
        }
        __syncthreads();

        s8v af[4], bf[4];
        #pragma unroll
        for (int i = 0; i < 4; i++)
            af[i] = *(const s8v*)&a_lds[wr * 64 + i * 16 + fr][kg * 8];
        #pragma unroll
        for (int j = 0; j < 4; j++)
            bf[j] = *(const s8v*)&b_lds[wc * 64 + j * 16 + fr][kg * 8];
        #pragma unroll
        for (int i = 0; i < 4; i++)
            #pragma unroll
            for (int j = 0; j < 4; j++)
                acc[i][j] = __builtin_amdgcn_mfma_f32_16x16x32_bf16(
                    af[i], bf[j], acc[i][j], 0, 0, 0);
    }

    #pragma unroll
    for (int i = 0; i < 4; i++)
        #pragma unroll
        for (int j = 0; j < 4; j++)
            #pragma unroll
            for (int r = 0; r < 4; r++) {
                int row = m0 + wr * 64 + i * 16 + kg * 4 + r;
                int col = n0 + wc * 64 + j * 16 + fr;
                stm(C, cOff + (size_t)row * N + col, cm, acc[i][j][r]);
            }
}

// ---------------------------------------------------------------------------
// rotary + RMS-norm; optional second bf16 store (kout) for attention's K copy.
// ---------------------------------------------------------------------------
__global__ __launch_bounds__(256) void rot_rms_kernel(
    void* __restrict__ p, size_t pOff, const int* __restrict__ pF,
    const void* __restrict__ cosb, const void* __restrict__ sinb,
    const int* __restrict__ eF, int ldiv, bf16* __restrict__ kout)
{
    const int pm = *pF, em = *eF;
    const int row  = blockIdx.x * 4 + (threadIdx.x >> 6);
    const int lane = threadIdx.x & 63;
    const int l    = (row / ldiv) % L_;
    const size_t base = pOff + (size_t)row * HD_;

    float x1 = ldm(p, base + lane,      pm);
    float x2 = ldm(p, base + lane + 64, pm);
    float c  = ldm(cosb, (size_t)l * 64 + lane, em);
    float s  = ldm(sinb, (size_t)l * 64 + lane, em);
    float y1 =  x1 * c + x2 * s;
    float y2 = -x1 * s + x2 * c;

    float sq = y1 * y1 + y2 * y2;
    #pragma unroll
    for (int off = 32; off > 0; off >>= 1) sq += __shfl_xor(sq, off);
    float rinv = rsqrtf(sq * (1.0f / 128.0f) + 1.1920929e-07f);

    stm(p, base + lane,      pm, y1 * rinv);
    stm(p, base + lane + 64, pm, y2 * rinv);
    if (kout) {
        kout[(size_t)row * HD_ + lane]      = __float2bfloat16(y1 * rinv);
        kout[(size_t)row * HD_ + lane + 64] = __float2bfloat16(y2 * rinv);
    }
}

// ---------------------------------------------------------------------------
// V transpose: newv [B][L][HD] (ext dtype) -> vt [B][HD][L] bf16
// ---------------------------------------------------------------------------
__global__ __launch_bounds__(256) void transpose_v_kernel(
    const void* __restrict__ v, size_t vOff, const int* __restrict__ vF,
    bf16* __restrict__ vt)
{
    const int m = *vF;
    const int l0 = blockIdx.x * 32, c0 = blockIdx.y * 32, b = blockIdx.z;
    __shared__ bf16 tile[32][36];
    const int t = threadIdx.x;
    {
        int r = t >> 3, c4 = (t & 7) * 4;
        size_t g = vOff + (size_t)(b * L_ + l0 + r) * HD_ + c0 + c4;
        #pragma unroll
        for (int e = 0; e < 4; e++)
            tile[r][c4 + e] = __float2bfloat16(ldm(v, g + e, m));
    }
    __syncthreads();
    {
        int c = t >> 3, r4 = (t & 7) * 4;
        bf16 tmp[4];
        #pragma unroll
        for (int e = 0; e < 4; e++) tmp[e] = tile[r4 + e][c];
        *(s4v*)&vt[(size_t)(b * HD_ + c0 + c) * L_ + l0 + r4] = *(s4v*)&tmp[0];
    }
}

// ---------------------------------------------------------------------------
// MFMA causal flash attention, S^T formulation.
// Block = (128 q-rows, h, b), 4 waves; wave w owns q-rows [32w, 32w+32)
// as two 16-row strips. S^T = K·Q^T so the MFMA C-layout gives each lane
// 4 consecutive KEYS at one q-row -> P written as ds_write_b64 (conflict-
// free), softmax stats are one scalar per lane per strip, and O^T output
// gives 4 consecutive hd elements -> b64 global stores.
// l0 reversed so longest (most k-tiles) blocks dispatch first.
// ---------------------------------------------------------------------------
__global__ __launch_bounds__(256, 3) void attn_kernel(
    const bf16* __restrict__ q,
    const bf16* __restrict__ kbuf,
    const bf16* __restrict__ vt,
    bf16* __restrict__ o)
{
    const int l0 = ((int)gridDim.x - 1 - (int)blockIdx.x) * 128;
    const int h  = blockIdx.y, b = blockIdx.z;
    const int t  = threadIdx.x, w = t >> 6, ln = t & 63;
    const int fr = ln & 15, kg = ln >> 4;

    __shared__ bf16 k_lds[64][136];    // K tile  [key][hd]   (+8 pad)
    __shared__ bf16 vt_lds[128][72];   // V^T tile [hd][key]  (+8 pad)
    __shared__ bf16 p_lds[128][72];    // P tile  [qrow][key] (+8 pad)

    // Q fragments (loop-invariant): [strip][kstep]
    s8v qf[2][4];
    #pragma unroll
    for (int s = 0; s < 2; s++) {
        size_t base = (size_t)(b * L_ + l0 + w * 32 + s * 16 + fr) * D_
                      + h * HD_ + kg * 8;
        #pragma unroll
        for (int kst = 0; kst < 4; kst++)
            qf[s][kst] = *(const s8v*)(q + base + kst * 32);
    }

    float m_i[2] = {-3.0e38f, -3.0e38f};
    float l_i[2] = {0.f, 0.f};
    f4v o_acc[8][2];
    #pragma unroll
    for (int mt = 0; mt < 8; mt++)
        #pragma unroll
        for (int s = 0; s < 2; s++)
            #pragma unroll
            for (int r = 0; r < 4; r++) o_acc[mt][s][r] = 0.f;

    const float scale = 0.08838834764831845f;  // 1/sqrt(128)
    const int qmax_w = l0 + w * 32 + 31;       // wave's max q-row
    const int kend   = l0 + 128;

    for (int kb = 0; kb < kend; kb += 64) {
        __syncthreads();
        // ---- stage K tile (64 keys x 128 hd) ----
        {
            int r = t >> 2, c0 = (t & 3) * 32;
            const s8v* src = (const s8v*)(kbuf + (size_t)(b * L_ + kb + r) * HD_ + c0);
            #pragma unroll
            for (int s = 0; s < 4; s++)
                *(s8v*)&k_lds[r][c0 + s * 8] = src[s];
        }
        // ---- stage V^T tile (128 hd x 64 keys) ----
        {
            int r = t >> 1, c0 = (t & 1) * 32;
            const s8v* src = (const s8v*)(vt + (size_t)(b * HD_ + r) * L_ + kb + c0);
            #pragma unroll
            for (int s = 0; s < 4; s++)
                *(s8v*)&vt_lds[r][c0 + s * 8] = src[s];
        }
        __syncthreads();

        if (kb <= qmax_w) {  // wave-uniform: skip fully-masked tiles
            // ---- S^T = K · Q^T : A = K rows (m=key), B = Q (n=qrow) ----
            f4v sacc[4][2];
            #pragma unroll
            for (int jm = 0; jm < 4; jm++)
                #pragma unroll
                for (int s = 0; s < 2; s++)
                    #pragma unroll
                    for (int r = 0; r < 4; r++) sacc[jm][s][r] = 0.f;
            #pragma unroll
            for (int kst = 0; kst < 4; kst++) {
                #pragma unroll
                for (int jm = 0; jm < 4; jm++) {
                    s8v af = *(const s8v*)&k_lds[jm * 16 + fr][kst * 32 + kg * 8];
                    #pragma unroll
                    for (int s = 0; s < 2; s++)
                        sacc[jm][s] = __builtin_amdgcn_mfma_f32_16x16x32_bf16(
                            af, qf[s][kst], sacc[jm][s], 0, 0, 0);
                }
            }

            // ---- online softmax per strip (qrow = lane's fr) ----
            #pragma unroll
            for (int s = 0; s < 2; s++) {
                const int qrow = l0 + w * 32 + s * 16 + fr;
                float sv[4][4];
                float mx = -1.0e30f;
                #pragma unroll
                for (int jm = 0; jm < 4; jm++)
                    #pragma unroll
                    for (int r = 0; r < 4; r++) {
                        int key = kb + jm * 16 + kg * 4 + r;
                        float v = sacc[jm][s][r] * scale;
                        v = (key <= qrow) ? v : -1.0e30f;
                        sv[jm][r] = v;
                        mx = fmaxf(mx, v);
                    }
                mx = fmaxf(mx, __shfl_xor(mx, 16));
                mx = fmaxf(mx, __shfl_xor(mx, 32));
                float mn = fmaxf(m_i[s], mx);
                float alpha = __expf(m_i[s] - mn);
                m_i[s] = mn;
                float rsum = 0.f;
                #pragma unroll
                for (int jm = 0; jm < 4; jm++) {
                    bf16 pb[4];
                    #pragma unroll
                    for (int r = 0; r < 4; r++) {
                        float pe = __expf(sv[jm][r] - mn);
                        rsum += pe;
                        pb[r] = __float2bfloat16(pe);
                    }
                    *(s4v*)&p_lds[w * 32 + s * 16 + fr][jm * 16 + kg * 4] =
                        *(s4v*)&pb[0];
                }
                rsum += __shfl_xor(rsum, 16);
                rsum += __shfl_xor(rsum, 32);
                l_i[s] = l_i[s] * alpha + rsum;
                #pragma unroll
                for (int mt = 0; mt < 8; mt++)
                    #pragma unroll
                    for (int r = 0; r < 4; r++) o_acc[mt][s][r] *= alpha;
            }

            // ---- O^T += V^T · P^T : A = V^T rows (m=hd), B = P (n=qrow) ----
            #pragma unroll
            for (int ks = 0; ks < 2; ks++) {
                s8v pf[2];
                #pragma unroll
                for (int s = 0; s < 2; s++)
                    pf[s] = *(const s8v*)&p_lds[w * 32 + s * 16 + fr][ks * 32 + kg * 8];
                #pragma unroll
                for (int mt = 0; mt < 8; mt++) {
                    s8v vf = *(const s8v*)&vt_lds[mt * 16 + fr][ks * 32 + kg * 8];
                    #pragma unroll
                    for (int s = 0; s < 2; s++)
                        o_acc[mt][s] = __builtin_amdgcn_mfma_f32_16x16x32_bf16(
                            vf, pf[s], o_acc[mt][s], 0, 0, 0);
                }
            }
        }
    }

    // ---- epilogue: O^T C-layout -> 4 consecutive hd per lane -> b64 stores
    #pragma unroll
    for (int s = 0; s < 2; s++) {
        float rl = 1.f / l_i[s];
        size_t base = (size_t)(b * L_ + l0 + w * 32 + s * 16 + fr) * D_
                      + h * HD_ + kg * 4;
        #pragma unroll
        for (int mt = 0; mt < 8; mt++) {
            bf16 ob[4];
            #pragma unroll
            for (int r = 0; r < 4; r++)
                ob[r] = __float2bfloat16(o_acc[mt][s][r] * rl);
            *(s4v*)(o + base + mt * 16) = *(s4v*)&ob[0];
        }
    }
}

// ---------------------------------------------------------------------------
extern "C" void kernel_launch(void* const* d_in, const int* in_sizes, int n_in,
                              void* d_out, int out_size, void* d_ws, size_t ws_size,
                              hipStream_t stream)
{
    const void* x    = d_in[0];
    const void* cosb = d_in[1];
    const void* sinb = d_in[2];
    const void* Wq   = d_in[3];
    const void* Wk   = d_in[4];
    const void* Wv   = d_in[5];
    const void* Wo   = d_in[6];

    // ws: [flags 256 B][vtbuf 2 MiB][kbuf 2 MiB][qbuf 32 MiB]  (~36.25 MiB)
    int*  flags = (int*)d_ws;
    bf16* vtbuf = (bf16*)((char*)d_ws + 256);
    bf16* kbuf  = vtbuf + (size_t)B_ * HD_ * L_;
    bf16* qbuf  = kbuf  + (size_t)B_ * L_ * HD_;
    const int* EXT  = flags;
    const int* INT0 = flags + 1;

    const size_t kOff = (size_t)B_ * L_ * D_;
    const size_t vOff = kOff + (size_t)B_ * L_ * HD_;
    const int M = B_ * L_;  // 8192

    detect_kernel<<<1, 64, 0, stream>>>(x, flags);

    gemm_bt_kernel<<<dim3(D_ / 128,  M / 128), 256, 0, stream>>>(
        x, EXT, Wq, EXT, qbuf, 0, INT0, D_, D_);
    gemm_bt_kernel<<<dim3(HD_ / 128, M / 128), 256, 0, stream>>>(
        x, EXT, Wk, EXT, d_out, kOff, EXT, HD_, D_);
    gemm_bt_kernel<<<dim3(HD_ / 128, M / 128), 256, 0, stream>>>(
        x, EXT, Wv, EXT, d_out, vOff, EXT, HD_, D_);

    rot_rms_kernel<<<(M * H_) / 4, 256, 0, stream>>>(
        qbuf, 0, INT0, cosb, sinb, EXT, H_, nullptr);
    rot_rms_kernel<<<M / 4, 256, 0, stream>>>(
        d_out, kOff, EXT, cosb, sinb, EXT, 1, kbuf);

    transpose_v_kernel<<<dim3(L_ / 32, HD_ / 32, B_), 256, 0, stream>>>(
        d_out, vOff, EXT, vtbuf);

    // attention: reads qbuf/kbuf/vtbuf, writes output in-place into qbuf
    attn_kernel<<<dim3(L_ / 128, H_, B_), 256, 0, stream>>>(
        qbuf, kbuf, vtbuf, qbuf);

    gemm_bt_kernel<<<dim3(D_ / 128, M / 128), 256, 0, stream>>>(
        qbuf, INT0, Wo, EXT, d_out, 0, EXT, D_, D_);
}